// Round 7
// baseline (453.513 us; speedup 1.0000x reference)
//
#include <hip/hip_runtime.h>

// Fusedmax: out = sparsemax(prox_TV1D(x, alpha=1)) row-wise. B=4096, N=512, fp32.
//
// v8: TAUT-STRING FUNNEL TV (exact TV solution, O(n) amortized, NO rescans).
// v3-v7's ledger showed Condat's jump-restarts inflate step count 3-5x; the
// harness tolerance (v6 passed at 1.95e-3) admits any exact-TV algorithm.
// TV prox = slope of the shortest path ("taut string") through the tube
// r_i +- lam (r = prefix sums), pinned at (0,0) and (512, r_512). Funnel:
//   apex (ax,ay) + upper chain (convex: slopes increasing, CCW turns) +
//   lower chain (concave: slopes decreasing, CW turns).
//   addUpper(P): pop back while cross(prev,last,P) <= 0; if chain empties,
//     bend: while slope(a,P) < slope(a,lowerFront) emit segment a->front,
//     apex = front, popfront. Then push P. addLower mirrored. Close with B
//     walking whichever front blocks the straight apex->B line.
//   Stale (x <= ax) and dominated fronts are lazily dropped (safe: committed
//   path already cleared them / convexity argument).
// Chains: LDS arrays, top-2 entries register-cached; era-reset on empty.
// Hull of a Gaussian random walk ~ 2 ln n ~ 12 entries; CHN=192 is margin.
// Segments (constant-slope stretches) -> v4-verified deferred parallel
// replay (always ordered+disjoint here). Michelot sparsemax unchanged.

#define TVN 512
#define LAMBDA 1.0f
#define CHN 192

__device__ __forceinline__ float wave_reduce_sum(float v) {
#pragma unroll
    for (int off = 32; off > 0; off >>= 1) v += __shfl_xor(v, off, 64);
    return v;
}

// ---- chain helpers (upper: ub1=back, ub2=second-back; LDS holds 0..usz-3) ----
#define UFRONT(FX, FY) { if (usz >= 3) { float2 _f = uch[ulo]; FX=_f.x; FY=_f.y; } \
                         else if (usz == 2) { FX=ub2x; FY=ub2y; } else { FX=ub1x; FY=ub1y; } }
#define LFRONT(FX, FY) { if (lsz >= 3) { float2 _f = lch[llo]; FX=_f.x; FY=_f.y; } \
                         else if (lsz == 2) { FX=lb2x; FY=lb2y; } else { FX=lb1x; FY=lb1y; } }
#define UENT1(FX, FY)  { if (usz >= 4) { float2 _f = uch[ulo+1]; FX=_f.x; FY=_f.y; } \
                         else if (usz == 3) { FX=ub2x; FY=ub2y; } else { FX=ub1x; FY=ub1y; } }
#define LENT1(FX, FY)  { if (lsz >= 4) { float2 _f = lch[llo+1]; FX=_f.x; FY=_f.y; } \
                         else if (lsz == 3) { FX=lb2x; FY=lb2y; } else { FX=lb1x; FY=lb1y; } }
#define POPF_U() { if (usz >= 3) ++ulo; --usz; }
#define POPF_L() { if (lsz >= 3) ++llo; --lsz; }
#define POPB_U() { --usz; ub1x=ub2x; ub1y=ub2y; \
                   if (usz >= 2) { float2 _e = uch[ulo+usz-2]; ub2x=_e.x; ub2y=_e.y; } }
#define POPB_L() { --lsz; lb1x=lb2x; lb1y=lb2y; \
                   if (lsz >= 2) { float2 _e = lch[llo+lsz-2]; lb2x=_e.x; lb2y=_e.y; } }
#define PUSH_U(PX, PY) { if (usz >= 2) { uch[ulo+usz-2] = make_float2(ub2x, ub2y); ub2x=ub1x; ub2y=ub1y; } \
                         else if (usz == 1) { ub2x=ub1x; ub2y=ub1y; } else { ulo = 0; } \
                         ub1x=(PX); ub1y=(PY); ++usz; }
#define PUSH_L(PX, PY) { if (lsz >= 2) { lch[llo+lsz-2] = make_float2(lb2x, lb2y); lb2x=lb1x; lb2y=lb1y; } \
                         else if (lsz == 1) { lb2x=lb1x; lb2y=lb1y; } else { llo = 0; } \
                         lb1x=(PX); lb1y=(PY); ++lsz; }

#define EMIT(VX, VY) { const float _s = ((VY) - ay) / ((VX) - ax); \
                       const int _k0 = (int)ax; const int _k1 = (int)(VX) - 1; \
                       segi[ns] = (_k0 << 16) | _k1; segv[ns] = _s; ++ns; }

#define ADDUPPER(XF, UP) {                                                        \
    for (;;) {                                                                    \
        if (usz >= 2) {                                                           \
            const float _cr = (ub1x-ub2x)*((UP)-ub2y) - (ub1y-ub2y)*((XF)-ub2x);  \
            if (_cr > 0.0f) break;                                                \
            POPB_U();                                                             \
        } else if (usz == 1) {                                                    \
            const float _cr = (ub1x-ax)*((UP)-ay) - (ub1y-ay)*((XF)-ax);          \
            if (_cr > 0.0f) break;                                                \
            usz = 0;                                                              \
        } else {                                                                  \
            while (lsz > 0) {                                                     \
                float _fx, _fy; LFRONT(_fx, _fy);                                 \
                if (_fx <= ax) { POPF_L(); continue; }                            \
                if (lsz >= 2) { float _gx, _gy; LENT1(_gx, _gy);                  \
                    if ((_fx-ax)*(_gy-ay) - (_fy-ay)*(_gx-ax) >= 0.0f) { POPF_L(); continue; } } \
                const float _cr = (_fx-ax)*((UP)-ay) - (_fy-ay)*((XF)-ax);        \
                if (_cr >= 0.0f) break;                                           \
                EMIT(_fx, _fy); ax = _fx; ay = _fy; POPF_L();                     \
            }                                                                     \
            break;                                                                \
        }                                                                         \
    }                                                                             \
    PUSH_U((XF), (UP));                                                           \
}

#define ADDLOWER(XF, LP) {                                                        \
    for (;;) {                                                                    \
        if (lsz >= 2) {                                                           \
            const float _cr = (lb1x-lb2x)*((LP)-lb2y) - (lb1y-lb2y)*((XF)-lb2x);  \
            if (_cr < 0.0f) break;                                                \
            POPB_L();                                                             \
        } else if (lsz == 1) {                                                    \
            const float _cr = (lb1x-ax)*((LP)-ay) - (lb1y-ay)*((XF)-ax);          \
            if (_cr < 0.0f) break;                                                \
            lsz = 0;                                                              \
        } else {                                                                  \
            while (usz > 0) {                                                     \
                float _fx, _fy; UFRONT(_fx, _fy);                                 \
                if (_fx <= ax) { POPF_U(); continue; }                            \
                if (usz >= 2) { float _gx, _gy; UENT1(_gx, _gy);                  \
                    if ((_fx-ax)*(_gy-ay) - (_fy-ay)*(_gx-ax) <= 0.0f) { POPF_U(); continue; } } \
                const float _cr = (_fx-ax)*((LP)-ay) - (_fy-ay)*((XF)-ax);        \
                if (_cr <= 0.0f) break;                                           \
                EMIT(_fx, _fy); ax = _fx; ay = _fy; POPF_U();                     \
            }                                                                     \
            break;                                                                \
        }                                                                         \
    }                                                                             \
    PUSH_L((XF), (LP));                                                           \
}

#define PROCESS(W) {                                                              \
    rsum += (W); xf += 1.0f;                                                      \
    const float _uP = rsum + lam;                                                 \
    const float _lP = rsum - lam;                                                 \
    ADDUPPER(xf, _uP);                                                            \
    ADDLOWER(xf, _lP);                                                            \
}

__global__ __launch_bounds__(64) void fusedmax_kernel(const float* __restrict__ xin,
                                                      float* __restrict__ out) {
    __shared__ alignas(16) float row[TVN];
    __shared__ float2 uch[CHN];
    __shared__ float2 lch[CHN];
    __shared__ int   segi[TVN];
    __shared__ float segv[TVN];
    __shared__ int nsS;

    const int t = threadIdx.x;                 // 0..63
    const long long r = blockIdx.x;
    const float lam = LAMBDA;

    // ---- stage row into LDS, coalesced (16B/lane) ----
    const float4* __restrict__ g4 = (const float4*)(xin + r * TVN);
    float4* s4 = (float4*)row;
    s4[t] = g4[t];
    s4[t + 64] = g4[t + 64];
    __syncthreads();

    // ---- taut-string funnel, serial on lane 0 (row stays pristine) ----
    if (t == 0) {
        float ax = 0.0f, ay = 0.0f;            // apex = (0, 0): r_0 pinned
        int usz = 0, lsz = 0, ulo = 0, llo = 0, ns = 0;
        float ub1x=0.f,ub1y=0.f,ub2x=0.f,ub2y=0.f;
        float lb1x=0.f,lb1y=0.f,lb2x=0.f,lb2y=0.f;
        float rsum = 0.0f, xf = 0.0f;

#pragma unroll 1
        for (int b = 0; b < TVN - 8; b += 8) { // knots 1..504
            const float w0=row[b+0], w1=row[b+1], w2=row[b+2], w3=row[b+3];
            const float w4=row[b+4], w5=row[b+5], w6=row[b+6], w7=row[b+7];
            PROCESS(w0) PROCESS(w1) PROCESS(w2) PROCESS(w3)
            PROCESS(w4) PROCESS(w5) PROCESS(w6) PROCESS(w7)
        }
        {                                      // knots 505..511, last y feeds close
            const float w0=row[TVN-8], w1=row[TVN-7], w2=row[TVN-6], w3=row[TVN-5];
            const float w4=row[TVN-4], w5=row[TVN-3], w6=row[TVN-2], w7=row[TVN-1];
            PROCESS(w0) PROCESS(w1) PROCESS(w2) PROCESS(w3)
            PROCESS(w4) PROCESS(w5) PROCESS(w6)
            rsum += w7;                        // r_512
        }

        // ---- close with B = (512, r_512), pinned endpoint ----
        const float Bx = (float)TVN, By = rsum;
        for (;;) {
            // lazily normalize fronts w.r.t. current apex
            while (lsz > 0) { float fx, fy; LFRONT(fx, fy);
                if (fx <= ax) { POPF_L(); continue; }
                if (lsz >= 2) { float gx, gy; LENT1(gx, gy);
                    if ((fx-ax)*(gy-ay) - (fy-ay)*(gx-ax) >= 0.0f) { POPF_L(); continue; } }
                break; }
            while (usz > 0) { float fx, fy; UFRONT(fx, fy);
                if (fx <= ax) { POPF_U(); continue; }
                if (usz >= 2) { float gx, gy; UENT1(gx, gy);
                    if ((fx-ax)*(gy-ay) - (fy-ay)*(gx-ax) <= 0.0f) { POPF_U(); continue; } }
                break; }
            if (lsz > 0) { float fx, fy; LFRONT(fx, fy);
                if ((fx-ax)*(By-ay) - (fy-ay)*(Bx-ax) < 0.0f) {
                    EMIT(fx, fy); ax = fx; ay = fy; POPF_L(); continue; } }
            if (usz > 0) { float fx, fy; UFRONT(fx, fy);
                if ((fx-ax)*(By-ay) - (fy-ay)*(Bx-ax) > 0.0f) {
                    EMIT(fx, fy); ax = fx; ay = fy; POPF_U(); continue; } }
            break;
        }
        EMIT(Bx, By);                          // final segment, ends at idx 511
        nsS = ns;
    }
    __syncthreads();

    // ---- segment replay: segments ordered+disjoint -> one lane per segment ----
    {
        const int n = nsS;
        for (int s = t; s < n; s += 64) {
            const int pk = segi[s];
            const float v = segv[s];
            const int i1 = pk & 0xffff;
            for (int i = (pk >> 16); i <= i1; ++i) row[i] = v;
        }
    }
    __syncthreads();

    // ---- sparsemax via Michelot fixed point (exact tau, no sort) ----
    float4 a = s4[t];
    float4 b = s4[t + 64];
    float v[8] = {a.x, a.y, a.z, a.w, b.x, b.y, b.z, b.w};

    float ls = v[0] + v[1] + v[2] + v[3] + v[4] + v[5] + v[6] + v[7];
    float S = wave_reduce_sum(ls);
    float tau = (S - 1.0f) * (1.0f / (float)TVN);   // support = all
    int cprev = TVN;
#pragma unroll 1
    for (int it = 0; it < 64; ++it) {
        float s = 0.0f, c = 0.0f;
#pragma unroll
        for (int j = 0; j < 8; ++j) {
            if (v[j] > tau) { s += v[j]; c += 1.0f; }
        }
        s = wave_reduce_sum(s);
        c = wave_reduce_sum(c);               // >= 1 always (tau < max)
        tau = (s - 1.0f) / c;
        int ci = (int)c;
        if (ci == cprev) break;               // support stabilized -> tau exact
        cprev = ci;
    }

    float4 oa, ob;
    oa.x = fmaxf(v[0] - tau, 0.0f);
    oa.y = fmaxf(v[1] - tau, 0.0f);
    oa.z = fmaxf(v[2] - tau, 0.0f);
    oa.w = fmaxf(v[3] - tau, 0.0f);
    ob.x = fmaxf(v[4] - tau, 0.0f);
    ob.y = fmaxf(v[5] - tau, 0.0f);
    ob.z = fmaxf(v[6] - tau, 0.0f);
    ob.w = fmaxf(v[7] - tau, 0.0f);
    float4* __restrict__ o4 = (float4*)(out + r * TVN);
    o4[t] = oa;
    o4[t + 64] = ob;
}

extern "C" void kernel_launch(void* const* d_in, const int* in_sizes, int n_in,
                              void* d_out, int out_size, void* d_ws, size_t ws_size,
                              hipStream_t stream) {
    const float* x = (const float*)d_in[0];
    float* out = (float*)d_out;
    const int rows = in_sizes[0] / TVN;       // 4096
    fusedmax_kernel<<<dim3(rows), dim3(64), 0, stream>>>(x, out);
}

// Round 8
// 263.307 us; speedup vs baseline: 1.7224x; 1.7224x over previous
//
#include <hip/hip_runtime.h>

// Fusedmax: out = sparsemax(prox_TV1D(x, alpha=1)) row-wise. B=4096, N=512, fp32.
//
// v9: BIDIRECTIONAL CONDAT. v3's 215us serial scan is the best per-step engine
// (v6 event-probe and v8 taut-string both lost: events are dense). The untouched
// axis is parallelism: 4096 rows = 4096 single-wave chains = only 16 waves/CU
// (grid-capped), VALUBusy 61%. Fix: TWO waves per row.
//   - Condat's pre-end-phase flushes are FINAL (contiguous from 0; future data
//     never alters them). TV-prox is reversal-symmetric. So wave 0 runs the
//     verified v3 scan forward on rowF and STOPS at the first jump with
//     nk >= 257 (rowF[0..nk-1] ⊇ [0..256] is the exact solution there); wave 1
//     runs the SAME scan on the reversed copy rowR, covering original [255..511].
//   - A wave that never stops (giant middle segment, rare) runs its verified
//     full path incl. end-phase -- still exact. End-phase has NO stop checks
//     (rewind makes mid-phase abort unsafe; completion is safe).
//   - Sparsemax: stitched gather (i<=256 from rowF else rowR[511-i]); both
//     waves compute Michelot redundantly; each writes its half of the output.
// Per-wave work halves; waves double to 8192 -> 32 waves/CU (16 wg x 2 waves),
// 8 waves/SIMD to cover branch/LDS stalls. Scan body = v3 verbatim + 1 stop line.

#define TVN 512
#define LAMBDA 1.0f
#define STOPK 257

__device__ __forceinline__ float wave_reduce_sum(float v) {
#pragma unroll
    for (int off = 32; off > 0; off >>= 1) v += __shfl_xor(v, off, 64);
    return v;
}

// v3's verified lane-0 Condat scan (batch-8 register lookahead, rcp clamps,
// in-place flushes, yLast end-phase) + early-exit when coverage reaches STOPK.
__device__ __forceinline__ void tv_scan_half(float* __restrict__ row) {
    const float lam = LAMBDA;
    const float yLast = row[TVN - 1];
    const float twolam = 2.0f * lam;
    int k = 0, k0 = 0, km = 0, kp = 0;
    float vmin = row[0] - lam, vmax = row[0] + lam;
    float umin = lam, umax = -lam;
    float cntf = 1.0f;                     // == (float)(k - k0 + 1)
    float yn;

#define ACCUM_STEP(W)                                                   \
    yn = (W);                                                           \
    if (yn + umin < vmin - lam) goto neg_jump;                          \
    if (yn + umax > vmax + lam) goto pos_jump;                          \
    ++k; cntf += 1.0f;                                                  \
    umin += yn - vmin;                                                  \
    umax += yn - vmax;                                                  \
    if (umin >= lam) {                                                  \
        vmin += (umin - lam) * __builtin_amdgcn_rcpf(cntf);             \
        umin = lam; km = k;                                             \
    }                                                                   \
    if (umax <= -lam) {                                                 \
        vmax += (umax + lam) * __builtin_amdgcn_rcpf(cntf);             \
        umax = -lam; kp = k;                                            \
    }                                                                   \
    if (k == TVN - 1) goto end_phase;

refill: {
        // k <= TVN-2 here: up to 8 accumulate steps from registers
        float w0 = row[k + 1], w1 = row[k + 2], w2 = row[k + 3], w3 = row[k + 4];
        float w4 = row[k + 5], w5 = row[k + 6], w6 = row[k + 7], w7 = row[k + 8];
        ACCUM_STEP(w0)
        ACCUM_STEP(w1)
        ACCUM_STEP(w2)
        ACCUM_STEP(w3)
        ACCUM_STEP(w4)
        ACCUM_STEP(w5)
        ACCUM_STEP(w6)
        ACCUM_STEP(w7)
        goto refill;
    }
#undef ACCUM_STEP

neg_jump: {
        for (int i = k0; i <= km; ++i) row[i] = vmin;
        int nk = km + 1;                   // <= TVN-1, untouched index
        if (nk >= STOPK) return;           // coverage [0, nk-1] ⊇ [0, 256]: done
        float ynk = row[nk];
        k = k0 = km = kp = nk;
        vmin = ynk;
        vmax = ynk + twolam;
        umin = lam;
        umax = -lam;
        cntf = 1.0f;
        if (k == TVN - 1) goto end_phase;  // unreachable after stop-check; kept
        goto refill;
    }

pos_jump: {
        for (int i = k0; i <= kp; ++i) row[i] = vmax;
        int nk = kp + 1;
        if (nk >= STOPK) return;           // coverage [0, nk-1] ⊇ [0, 256]: done
        float ynk = row[nk];
        k = k0 = km = kp = nk;
        vmax = ynk;
        vmin = ynk - twolam;
        umin = lam;
        umax = -lam;
        cntf = 1.0f;
        if (k == TVN - 1) goto end_phase;
        goto refill;
    }

end_phase: {
        // Reached only when no jump ever hit nk >= STOPK (giant tail segment):
        // run the verified full end phase to completion. No stop checks here
        // (rewind may rewrite earlier indices; completion is the safe path).
        for (;;) {
            if (umin < 0.0f) {             // end-phase negative jump
                for (int i = k0; i <= km; ++i) row[i] = vmin;
                int nk = km + 1;
                float ynk = (nk > TVN - 1) ? yLast : row[nk];
                if (nk > TVN - 1) nk = TVN - 1;
                k = k0 = km = nk;
                vmin = ynk;
                umin = lam;
                umax = ynk + lam - vmax;   // old vmax
                cntf = 1.0f;
                if (k == TVN - 1) continue;
                goto refill;
            } else if (umax > 0.0f) {      // end-phase positive jump
                for (int i = k0; i <= kp; ++i) row[i] = vmax;
                int nk = kp + 1;
                float ynk = (nk > TVN - 1) ? yLast : row[nk];
                if (nk > TVN - 1) nk = TVN - 1;
                k = k0 = kp = nk;
                vmax = ynk;
                umax = -lam;
                umin = ynk - lam - vmin;   // old vmin
                cntf = 1.0f;
                if (k == TVN - 1) continue;
                goto refill;
            } else {                       // finish
                float v = vmin + umin / (float)(k - k0 + 1);
                for (int i = k0; i < TVN; ++i) row[i] = v;
                return;
            }
        }
    }
}

__global__ __launch_bounds__(128) void fusedmax_kernel(const float* __restrict__ xin,
                                                       float* __restrict__ out) {
    __shared__ alignas(16) float rowF[TVN + 8];   // forward buffer (+8 lookahead pad)
    __shared__ alignas(16) float rowR[TVN + 8];   // reversed buffer

    const int t = threadIdx.x;                 // 0..127
    const int w = t >> 6;                      // wave id: 0 = forward, 1 = backward
    const int lane = t & 63;
    const long long r = blockIdx.x;

    // ---- stage: wave 0 -> rowF coalesced; wave 1 -> rowR reversed ----
    const float4* __restrict__ g4 = (const float4*)(xin + r * TVN);
    if (w == 0) {
        float4* s4 = (float4*)rowF;
        s4[lane] = g4[lane];
        s4[lane + 64] = g4[lane + 64];
        if (lane < 8) rowF[TVN + lane] = 0.0f;
    } else {
        float4 a = g4[lane];                   // elems 4*lane .. 4*lane+3
        float4 b = g4[lane + 64];              // elems 256+4*lane ..
        const int ba = 511 - 4 * lane;
        rowR[ba] = a.x; rowR[ba - 1] = a.y; rowR[ba - 2] = a.z; rowR[ba - 3] = a.w;
        const int bb = 255 - 4 * lane;
        rowR[bb] = b.x; rowR[bb - 1] = b.y; rowR[bb - 2] = b.z; rowR[bb - 3] = b.w;
        if (lane < 8) rowR[TVN + lane] = 0.0f;
    }
    __syncthreads();

    // ---- two independent half-scans (lane 0 of each wave) ----
    if (lane == 0) tv_scan_half(w ? rowR : rowF);
    __syncthreads();

    // ---- stitched gather: i<=256 from rowF, i>=257 from rowR[511-i] ----
    float v[8];
#pragma unroll
    for (int j = 0; j < 4; ++j) v[j] = rowF[4 * lane + j];          // 0..255
    {
        const int i0 = 256 + 4 * lane;
        v[4] = (i0 == 256) ? rowF[256] : rowR[511 - i0];
        v[5] = rowR[511 - (i0 + 1)];
        v[6] = rowR[511 - (i0 + 2)];
        v[7] = rowR[511 - (i0 + 3)];
    }

    // ---- sparsemax via Michelot fixed point (exact tau, no sort) ----
    float ls = v[0] + v[1] + v[2] + v[3] + v[4] + v[5] + v[6] + v[7];
    float S = wave_reduce_sum(ls);
    float tau = (S - 1.0f) * (1.0f / (float)TVN);   // support = all
    int cprev = TVN;
#pragma unroll 1
    for (int it = 0; it < 64; ++it) {
        float s = 0.0f, c = 0.0f;
#pragma unroll
        for (int j = 0; j < 8; ++j) {
            if (v[j] > tau) { s += v[j]; c += 1.0f; }
        }
        s = wave_reduce_sum(s);
        c = wave_reduce_sum(c);               // >= 1 always (tau < max)
        tau = (s - 1.0f) / c;
        int ci = (int)c;
        if (ci == cprev) break;               // support stabilized -> tau exact
        cprev = ci;
    }

    // ---- each wave writes its half of the row ----
    float4 o;
    if (w == 0) {
        o.x = fmaxf(v[0] - tau, 0.0f);
        o.y = fmaxf(v[1] - tau, 0.0f);
        o.z = fmaxf(v[2] - tau, 0.0f);
        o.w = fmaxf(v[3] - tau, 0.0f);
    } else {
        o.x = fmaxf(v[4] - tau, 0.0f);
        o.y = fmaxf(v[5] - tau, 0.0f);
        o.z = fmaxf(v[6] - tau, 0.0f);
        o.w = fmaxf(v[7] - tau, 0.0f);
    }
    float4* __restrict__ o4 = (float4*)(out + r * TVN);
    o4[lane + ((w == 0) ? 0 : 64)] = o;
}

extern "C" void kernel_launch(void* const* d_in, const int* in_sizes, int n_in,
                              void* d_out, int out_size, void* d_ws, size_t ws_size,
                              hipStream_t stream) {
    const float* x = (const float*)d_in[0];
    float* out = (float*)d_out;
    const int rows = in_sizes[0] / TVN;       // 4096
    fusedmax_kernel<<<dim3(rows), dim3(128), 0, stream>>>(x, out);
}